// Round 1
// baseline (421.082 us; speedup 1.0000x reference)
//
#include <hip/hip_runtime.h>

typedef unsigned short u16;
typedef __attribute__((ext_vector_type(8))) short bf16x8_t;
typedef __attribute__((ext_vector_type(4))) float f32x4_t;

__device__ __forceinline__ u16 f2bf(float x){
  union { float f; unsigned u; } v; v.f = x;
  unsigned r = v.u + 0x7FFFu + ((v.u >> 16) & 1u);
  return (u16)(r >> 16);
}
__device__ __forceinline__ float bf2f(u16 h){
  union { unsigned u; float f; } v; v.u = ((unsigned)h) << 16;
  return v.f;
}

// ---- X = [gene|expr] concat, split into hi/lo bf16. 8192 rows x 1024 cols ----
__global__ __launch_bounds__(256) void split_concat_kernel(
    const float* __restrict__ gene, const float* __restrict__ expr,
    u16* __restrict__ Xh, u16* __restrict__ Xl)
{
  size_t e = ((size_t)blockIdx.x * 256 + threadIdx.x) * 4;
  int row = (int)(e >> 10);
  int col = (int)(e & 1023);
  const float* src = (col < 512) ? (gene + (size_t)row * 512 + col)
                                 : (expr + (size_t)row * 512 + (col - 512));
  float4 v = *(const float4*)src;
  float a[4] = {v.x, v.y, v.z, v.w};
  u16 hs[4], ls[4];
#pragma unroll
  for (int i = 0; i < 4; i++){
    hs[i] = f2bf(a[i]);
    ls[i] = f2bf(a[i] - bf2f(hs[i]));
  }
  *(uint2*)(Xh + e) = make_uint2(hs[0] | ((unsigned)hs[1] << 16), hs[2] | ((unsigned)hs[3] << 16));
  *(uint2*)(Xl + e) = make_uint2(ls[0] | ((unsigned)ls[1] << 16), ls[2] | ((unsigned)ls[3] << 16));
}

// ---- W [K][N] f32 -> Wt hi/lo [N][K] bf16 (64x64 LDS-tiled transpose) ----
__global__ __launch_bounds__(256) void transpose_split_kernel(
    const float* __restrict__ W, u16* __restrict__ Wth, u16* __restrict__ Wtl,
    int K, int N)
{
  __shared__ float t[64][65];
  int k0 = blockIdx.x * 64, n0 = blockIdx.y * 64;
  int tid = threadIdx.x;
  int r = tid >> 4;            // 0..15
  int c4 = (tid & 15) * 4;     // 0..60
#pragma unroll
  for (int p = 0; p < 4; p++){
    int k = p * 16 + r;
    float4 v = *(const float4*)(W + (size_t)(k0 + k) * N + n0 + c4);
    t[c4 + 0][k] = v.x; t[c4 + 1][k] = v.y; t[c4 + 2][k] = v.z; t[c4 + 3][k] = v.w;
  }
  __syncthreads();
#pragma unroll
  for (int p = 0; p < 4; p++){
    int n = p * 16 + r;
    u16 hs[4], ls[4];
#pragma unroll
    for (int i = 0; i < 4; i++){
      float x = t[n][c4 + i];
      hs[i] = f2bf(x);
      ls[i] = f2bf(x - bf2f(hs[i]));
    }
    size_t o = (size_t)(n0 + n) * K + k0 + c4;
    *(uint2*)(Wth + o) = make_uint2(hs[0] | ((unsigned)hs[1] << 16), hs[2] | ((unsigned)hs[3] << 16));
    *(uint2*)(Wtl + o) = make_uint2(ls[0] | ((unsigned)ls[1] << 16), ls[2] | ((unsigned)ls[3] << 16));
  }
}

// ---- split-precision GEMM: C[M][512] = (Ah+Al)[M][K] @ (Bh+Bl)[K][512] + bias
// B given transposed [512][K]. BM=128 BN=64 BK=32. 256 thr = 4 waves (2x2 of 64x32).
// mode 0: write split bf16 row-major [.][512] (out0=hi,out1=lo)
// mode 1: write bf16 V transposed per head: out0[((b*8+h)*64+d)*2048 + s]
// mode 2: write f32 row-major (out0)
__global__ __launch_bounds__(256, 2) void gemm_split_kernel(
    const u16* __restrict__ Ah, const u16* __restrict__ Al, int lda,
    const u16* __restrict__ Bth, const u16* __restrict__ Btl, int K,
    const float* __restrict__ bias,
    void* __restrict__ out0, void* __restrict__ out1, int mode)
{
  constexpr int LDK = 40;   // padded k-stride (bank-conflict + 16B alignment: 80B rows)
  __shared__ __align__(16) u16 sAh[128 * LDK], sAl[128 * LDK];
  __shared__ __align__(16) u16 sBh[64 * LDK],  sBl[64 * LDK];
  int tid = threadIdx.x;
  int lane = tid & 63, w = tid >> 6, quad = lane >> 4, l15 = lane & 15;
  int wm = w & 1, wn = w >> 1;
  int m0 = blockIdx.x * 128, n0 = blockIdx.y * 64;

  f32x4_t acc[4][2];
#pragma unroll
  for (int i = 0; i < 4; i++)
#pragma unroll
    for (int j = 0; j < 2; j++)
#pragma unroll
      for (int r = 0; r < 4; r++) acc[i][j][r] = 0.f;

  int srA = tid >> 1;            // 0..127
  int scA = (tid & 1) * 16;      // 0,16
  int srB = tid >> 2;            // 0..63
  int scB = (tid & 3) * 8;       // 0,8,16,24
  const u16* pAh = Ah + (size_t)(m0 + srA) * lda + scA;
  const u16* pAl = Al + (size_t)(m0 + srA) * lda + scA;
  const u16* pBh = Bth + (size_t)(n0 + srB) * K + scB;
  const u16* pBl = Btl + (size_t)(n0 + srB) * K + scB;

  for (int k0 = 0; k0 < K; k0 += 32){
    uint4 a0 = *(const uint4*)(pAh + k0);
    uint4 a1 = *(const uint4*)(pAh + k0 + 8);
    uint4 l0 = *(const uint4*)(pAl + k0);
    uint4 l1 = *(const uint4*)(pAl + k0 + 8);
    uint4 b0 = *(const uint4*)(pBh + k0);
    uint4 b1 = *(const uint4*)(pBl + k0);
    __syncthreads();
    *(uint4*)&sAh[srA * LDK + scA]     = a0;
    *(uint4*)&sAh[srA * LDK + scA + 8] = a1;
    *(uint4*)&sAl[srA * LDK + scA]     = l0;
    *(uint4*)&sAl[srA * LDK + scA + 8] = l1;
    *(uint4*)&sBh[srB * LDK + scB] = b0;
    *(uint4*)&sBl[srB * LDK + scB] = b1;
    __syncthreads();

    bf16x8_t aH[4], aL[4], bH[2], bL[2];
#pragma unroll
    for (int mi = 0; mi < 4; mi++){
      int ad = (wm * 64 + mi * 16 + l15) * LDK + quad * 8;
      aH[mi] = *(const bf16x8_t*)&sAh[ad];
      aL[mi] = *(const bf16x8_t*)&sAl[ad];
    }
#pragma unroll
    for (int ni = 0; ni < 2; ni++){
      int bd = (wn * 32 + ni * 16 + l15) * LDK + quad * 8;
      bH[ni] = *(const bf16x8_t*)&sBh[bd];
      bL[ni] = *(const bf16x8_t*)&sBl[bd];
    }
#pragma unroll
    for (int mi = 0; mi < 4; mi++)
#pragma unroll
      for (int ni = 0; ni < 2; ni++){
        acc[mi][ni] = __builtin_amdgcn_mfma_f32_16x16x32_bf16(aH[mi], bH[ni], acc[mi][ni], 0, 0, 0);
        acc[mi][ni] = __builtin_amdgcn_mfma_f32_16x16x32_bf16(aH[mi], bL[ni], acc[mi][ni], 0, 0, 0);
        acc[mi][ni] = __builtin_amdgcn_mfma_f32_16x16x32_bf16(aL[mi], bH[ni], acc[mi][ni], 0, 0, 0);
      }
  }

#pragma unroll
  for (int mi = 0; mi < 4; mi++)
#pragma unroll
    for (int ni = 0; ni < 2; ni++){
      int gn = n0 + wn * 32 + ni * 16 + l15;
      float bs = bias[gn];
      int gm0 = m0 + wm * 64 + mi * 16 + quad * 4;
#pragma unroll
      for (int r = 0; r < 4; r++){
        float v = acc[mi][ni][r] + bs;
        int gm = gm0 + r;
        if (mode == 0){
          u16 hb = f2bf(v);
          ((u16*)out0)[(size_t)gm * 512 + gn] = hb;
          ((u16*)out1)[(size_t)gm * 512 + gn] = f2bf(v - bf2f(hb));
        } else if (mode == 1){
          int bb = gm >> 11, s = gm & 2047;
          int hh = gn >> 6, d = gn & 63;
          ((u16*)out0)[((size_t)((bb * 8 + hh) * 64 + d) << 11) + s] = f2bf(v);
        } else {
          ((float*)out0)[(size_t)gm * 512 + gn] = v;
        }
      }
    }
}

// ---- flash attention with M-masked renormalized softmax ----
// out[q][d] = sum_k (M*e)[q][k] V[k][d] / sum_k (M*e)[q][k],  e = exp(scale*qk*M - rowmax)
// grid (S/64, B*H), block 256 = 4 waves, wave w handles 16 q rows.
__global__ __launch_bounds__(256, 2) void flash_kernel(
    const u16* __restrict__ Qh, const u16* __restrict__ Ql,
    const u16* __restrict__ Kh, const u16* __restrict__ Kl,
    const u16* __restrict__ Vt, const float* __restrict__ Mm,
    u16* __restrict__ Oh, u16* __restrict__ Ol)
{
  constexpr int LK = 72;  // padded row length (144B rows, 16B aligned)
  __shared__ __align__(16) u16 sKh[64 * LK], sKl[64 * LK], sVt[64 * LK], sP[64 * LK];
  int tid = threadIdx.x, lane = tid & 63, w = tid >> 6, quad = lane >> 4, l15 = lane & 15;
  int bh = blockIdx.y, b = bh >> 3, h = bh & 7;
  int q0 = blockIdx.x * 64;
  const float scale = 0.125f;

  // Q fragments (held in registers for whole kernel)
  int qrow = q0 + w * 16 + l15;
  const u16* qpH = Qh + ((size_t)(b * 2048 + qrow)) * 512 + h * 64 + quad * 8;
  const u16* qpL = Ql + ((size_t)(b * 2048 + qrow)) * 512 + h * 64 + quad * 8;
  bf16x8_t qH[2], qL[2];
  qH[0] = *(const bf16x8_t*)qpH;        qH[1] = *(const bf16x8_t*)(qpH + 32);
  qL[0] = *(const bf16x8_t*)qpL;        qL[1] = *(const bf16x8_t*)(qpL + 32);

  float mrow[4] = {-3e38f, -3e38f, -3e38f, -3e38f};
  float lrow[4] = {0.f, 0.f, 0.f, 0.f};
  f32x4_t Oacc[4];
#pragma unroll
  for (int ni = 0; ni < 4; ni++)
#pragma unroll
    for (int r = 0; r < 4; r++) Oacc[ni][r] = 0.f;

  int sr = tid >> 2, sc = (tid & 3) * 16;
  const u16* gKh = Kh + ((size_t)(b * 2048 + sr)) * 512 + h * 64 + sc;
  const u16* gKl = Kl + ((size_t)(b * 2048 + sr)) * 512 + h * 64 + sc;
  const u16* gVt = Vt + ((size_t)(bh * 64 + sr)) * 2048 + sc;
  const float* Mbase = Mm + (size_t)b * 2048 * 2048;

  for (int k0 = 0; k0 < 2048; k0 += 64){
    uint4 a0 = *(const uint4*)(gKh + (size_t)k0 * 512);
    uint4 a1 = *(const uint4*)(gKh + (size_t)k0 * 512 + 8);
    uint4 c0 = *(const uint4*)(gKl + (size_t)k0 * 512);
    uint4 c1 = *(const uint4*)(gKl + (size_t)k0 * 512 + 8);
    uint4 v0 = *(const uint4*)(gVt + k0);
    uint4 v1 = *(const uint4*)(gVt + k0 + 8);
    __syncthreads();
    *(uint4*)&sKh[sr * LK + sc]     = a0;  *(uint4*)&sKh[sr * LK + sc + 8] = a1;
    *(uint4*)&sKl[sr * LK + sc]     = c0;  *(uint4*)&sKl[sr * LK + sc + 8] = c1;
    *(uint4*)&sVt[sr * LK + sc]     = v0;  *(uint4*)&sVt[sr * LK + sc + 8] = v1;
    __syncthreads();

    // scores = Q . K^T (split-bf16, 3 MFMAs per step)
    f32x4_t Sacc[4];
#pragma unroll
    for (int ni = 0; ni < 4; ni++)
#pragma unroll
      for (int r = 0; r < 4; r++) Sacc[ni][r] = 0.f;
#pragma unroll
    for (int ni = 0; ni < 4; ni++){
      int kb = (ni * 16 + l15) * LK;
#pragma unroll
      for (int ds = 0; ds < 2; ds++){
        bf16x8_t kH = *(const bf16x8_t*)&sKh[kb + ds * 32 + quad * 8];
        bf16x8_t kL = *(const bf16x8_t*)&sKl[kb + ds * 32 + quad * 8];
        Sacc[ni] = __builtin_amdgcn_mfma_f32_16x16x32_bf16(qH[ds], kH, Sacc[ni], 0, 0, 0);
        Sacc[ni] = __builtin_amdgcn_mfma_f32_16x16x32_bf16(qH[ds], kL, Sacc[ni], 0, 0, 0);
        Sacc[ni] = __builtin_amdgcn_mfma_f32_16x16x32_bf16(qL[ds], kH, Sacc[ni], 0, 0, 0);
      }
    }

    // s = scale * qk * M ; online max / rescale ; P = M * exp(s - m)
    float Mv[4][4], Sv[4][4], mx[4];
#pragma unroll
    for (int r = 0; r < 4; r++) mx[r] = -3e38f;
#pragma unroll
    for (int ni = 0; ni < 4; ni++)
#pragma unroll
      for (int r = 0; r < 4; r++){
        int q = q0 + w * 16 + quad * 4 + r;
        int kk = k0 + ni * 16 + l15;
        float mval = Mbase[(size_t)q * 2048 + kk];
        Mv[ni][r] = mval;
        float s = Sacc[ni][r] * scale * mval;
        Sv[ni][r] = s;
        mx[r] = fmaxf(mx[r], s);
      }
#pragma unroll
    for (int r = 0; r < 4; r++){
#pragma unroll
      for (int off = 1; off < 16; off <<= 1)
        mx[r] = fmaxf(mx[r], __shfl_xor(mx[r], off));
      float mn = fmaxf(mrow[r], mx[r]);
      float alpha = __expf(mrow[r] - mn);
      mrow[r] = mn;
      lrow[r] *= alpha;
#pragma unroll
      for (int ni = 0; ni < 4; ni++) Oacc[ni][r] *= alpha;
    }
    float ps[4] = {0.f, 0.f, 0.f, 0.f};
#pragma unroll
    for (int ni = 0; ni < 4; ni++)
#pragma unroll
      for (int r = 0; r < 4; r++){
        float p = Mv[ni][r] * __expf(Sv[ni][r] - mrow[r]);
        ps[r] += p;
        sP[(w * 16 + quad * 4 + r) * LK + ni * 16 + l15] = f2bf(p);
      }
#pragma unroll
    for (int r = 0; r < 4; r++){
#pragma unroll
      for (int off = 1; off < 16; off <<= 1)
        ps[r] += __shfl_xor(ps[r], off);
      lrow[r] += ps[r];
    }

    // O += P @ V   (P bf16, V bf16; wave-private sP region, no barrier needed)
#pragma unroll
    for (int ds = 0; ds < 2; ds++){
      bf16x8_t pf = *(const bf16x8_t*)&sP[(w * 16 + l15) * LK + ds * 32 + quad * 8];
#pragma unroll
      for (int ni = 0; ni < 4; ni++){
        bf16x8_t vf = *(const bf16x8_t*)&sVt[(ni * 16 + l15) * LK + ds * 32 + quad * 8];
        Oacc[ni] = __builtin_amdgcn_mfma_f32_16x16x32_bf16(pf, vf, Oacc[ni], 0, 0, 0);
      }
    }
  }

  // epilogue: normalize, split hi/lo, write row-major [8192][512]
#pragma unroll
  for (int r = 0; r < 4; r++){
    float inv = 1.0f / lrow[r];
    int q = q0 + w * 16 + quad * 4 + r;
    size_t rb = ((size_t)(b * 2048 + q)) * 512 + h * 64;
#pragma unroll
    for (int ni = 0; ni < 4; ni++){
      float v = Oacc[ni][r] * inv;
      int d = ni * 16 + l15;
      u16 hb = f2bf(v);
      Oh[rb + d] = hb;
      Ol[rb + d] = f2bf(v - bf2f(hb));
    }
  }
}

extern "C" void kernel_launch(void* const* d_in, const int* in_sizes, int n_in,
                              void* d_out, int out_size, void* d_ws, size_t ws_size,
                              hipStream_t stream)
{
  const float* gene = (const float*)d_in[0];
  const float* expr = (const float*)d_in[1];
  const float* Mm   = (const float*)d_in[2];
  const float* Wf   = (const float*)d_in[3];
  const float* bfv  = (const float*)d_in[4];
  const float* Wq   = (const float*)d_in[5];
  const float* bq   = (const float*)d_in[6];
  const float* Wk   = (const float*)d_in[7];
  const float* bk   = (const float*)d_in[8];
  const float* Wv   = (const float*)d_in[9];
  const float* bv   = (const float*)d_in[10];
  const float* Wo   = (const float*)d_in[11];
  const float* bo   = (const float*)d_in[12];
  float* out = (float*)d_out;

  char* ws = (char*)d_ws;
  size_t off = 0;
  auto alloc = [&](size_t bytes) -> void* {
    void* p = (void*)(ws + off);
    off += (bytes + 255) & ~(size_t)255;
    return p;
  };
  u16* Xh   = (u16*)alloc(8192ull * 1024 * 2);
  u16* Xl   = (u16*)alloc(8192ull * 1024 * 2);
  u16* Wfth = (u16*)alloc(512ull * 1024 * 2);
  u16* Wftl = (u16*)alloc(512ull * 1024 * 2);
  u16* Wqth = (u16*)alloc(512ull * 512 * 2);
  u16* Wqtl = (u16*)alloc(512ull * 512 * 2);
  u16* Wkth = (u16*)alloc(512ull * 512 * 2);
  u16* Wktl = (u16*)alloc(512ull * 512 * 2);
  u16* Wvth = (u16*)alloc(512ull * 512 * 2);
  u16* Wvtl = (u16*)alloc(512ull * 512 * 2);
  u16* Woth = (u16*)alloc(512ull * 512 * 2);
  u16* Wotl = (u16*)alloc(512ull * 512 * 2);
  u16* Fh   = (u16*)alloc(8192ull * 512 * 2);
  u16* Fl   = (u16*)alloc(8192ull * 512 * 2);
  u16* Qh   = (u16*)alloc(8192ull * 512 * 2);
  u16* Ql   = (u16*)alloc(8192ull * 512 * 2);
  u16* Kh   = (u16*)alloc(8192ull * 512 * 2);
  u16* Kl   = (u16*)alloc(8192ull * 512 * 2);
  u16* Vt   = (u16*)alloc(8192ull * 512 * 2);
  // X is dead after the V projection; attention output aliases it.
  u16* Oh = Xh;
  u16* Ol = Xl;

  split_concat_kernel<<<8192, 256, 0, stream>>>(gene, expr, Xh, Xl);
  transpose_split_kernel<<<dim3(16, 8), 256, 0, stream>>>(Wf, Wfth, Wftl, 1024, 512);
  transpose_split_kernel<<<dim3(8, 8),  256, 0, stream>>>(Wq, Wqth, Wqtl, 512, 512);
  transpose_split_kernel<<<dim3(8, 8),  256, 0, stream>>>(Wk, Wkth, Wktl, 512, 512);
  transpose_split_kernel<<<dim3(8, 8),  256, 0, stream>>>(Wv, Wvth, Wvtl, 512, 512);
  transpose_split_kernel<<<dim3(8, 8),  256, 0, stream>>>(Wo, Woth, Wotl, 512, 512);

  // fused = X @ Wf + bf   -> split bf16
  gemm_split_kernel<<<dim3(64, 8), 256, 0, stream>>>(Xh, Xl, 1024, Wfth, Wftl, 1024, bfv, Fh, Fl, 0);
  // Q = fused @ Wq + bq ; K = fused @ Wk + bk  -> split bf16 row-major
  gemm_split_kernel<<<dim3(64, 8), 256, 0, stream>>>(Fh, Fl, 512, Wqth, Wqtl, 512, bq, Qh, Ql, 0);
  gemm_split_kernel<<<dim3(64, 8), 256, 0, stream>>>(Fh, Fl, 512, Wkth, Wktl, 512, bk, Kh, Kl, 0);
  // V = expr @ Wv + bv -> bf16, transposed per head [b][h][d][s]
  gemm_split_kernel<<<dim3(64, 8), 256, 0, stream>>>(Xh + 512, Xl + 512, 1024, Wvth, Wvtl, 512, bv, Vt, nullptr, 1);
  // attention
  flash_kernel<<<dim3(32, 32), 256, 0, stream>>>(Qh, Ql, Kh, Kl, Vt, Mm, Oh, Ol);
  // out = O @ Wo + bo -> f32
  gemm_split_kernel<<<dim3(64, 8), 256, 0, stream>>>(Oh, Ol, 512, Woth, Wotl, 512, bo, out, nullptr, 2);

  (void)in_sizes; (void)n_in; (void)out_size; (void)ws_size;
}

// Round 2
// 372.949 us; speedup vs baseline: 1.1291x; 1.1291x over previous
//
#include <hip/hip_runtime.h>

typedef unsigned short u16;
typedef __attribute__((ext_vector_type(8))) short bf16x8_t;
typedef __attribute__((ext_vector_type(4))) float f32x4_t;

__device__ __forceinline__ u16 f2bf(float x){
  union { float f; unsigned u; } v; v.f = x;
  unsigned r = v.u + 0x7FFFu + ((v.u >> 16) & 1u);
  return (u16)(r >> 16);
}
__device__ __forceinline__ float bf2f(u16 h){
  union { unsigned u; float f; } v; v.u = ((unsigned)h) << 16;
  return v.f;
}

// async global->LDS DMA, 16B per lane. lds dest must be wave-uniform base;
// data lands at base + lane*16.
__device__ __forceinline__ void gl2lds16(const u16* g, u16* l){
  __builtin_amdgcn_global_load_lds((const __attribute__((address_space(1))) void*)g,
                                   (__attribute__((address_space(3))) void*)l, 16, 0, 0);
}

// ---- X = [gene|expr] concat, split into hi/lo bf16. 8192 rows x 1024 cols ----
__global__ __launch_bounds__(256) void split_concat_kernel(
    const float* __restrict__ gene, const float* __restrict__ expr,
    u16* __restrict__ Xh, u16* __restrict__ Xl)
{
  size_t e = ((size_t)blockIdx.x * 256 + threadIdx.x) * 4;
  int row = (int)(e >> 10);
  int col = (int)(e & 1023);
  const float* src = (col < 512) ? (gene + (size_t)row * 512 + col)
                                 : (expr + (size_t)row * 512 + (col - 512));
  float4 v = *(const float4*)src;
  float a[4] = {v.x, v.y, v.z, v.w};
  u16 hs[4], ls[4];
#pragma unroll
  for (int i = 0; i < 4; i++){
    hs[i] = f2bf(a[i]);
    ls[i] = f2bf(a[i] - bf2f(hs[i]));
  }
  *(uint2*)(Xh + e) = make_uint2(hs[0] | ((unsigned)hs[1] << 16), hs[2] | ((unsigned)hs[3] << 16));
  *(uint2*)(Xl + e) = make_uint2(ls[0] | ((unsigned)ls[1] << 16), ls[2] | ((unsigned)ls[3] << 16));
}

// ---- W [K][N] f32 -> Wt hi/lo [N][K] bf16 (64x64 LDS-tiled transpose) ----
__global__ __launch_bounds__(256) void transpose_split_kernel(
    const float* __restrict__ W, u16* __restrict__ Wth, u16* __restrict__ Wtl,
    int K, int N)
{
  __shared__ float t[64][65];
  int k0 = blockIdx.x * 64, n0 = blockIdx.y * 64;
  int tid = threadIdx.x;
  int r = tid >> 4;
  int c4 = (tid & 15) * 4;
#pragma unroll
  for (int p = 0; p < 4; p++){
    int k = p * 16 + r;
    float4 v = *(const float4*)(W + (size_t)(k0 + k) * N + n0 + c4);
    t[c4 + 0][k] = v.x; t[c4 + 1][k] = v.y; t[c4 + 2][k] = v.z; t[c4 + 3][k] = v.w;
  }
  __syncthreads();
#pragma unroll
  for (int p = 0; p < 4; p++){
    int n = p * 16 + r;
    u16 hs[4], ls[4];
#pragma unroll
    for (int i = 0; i < 4; i++){
      float x = t[n][c4 + i];
      hs[i] = f2bf(x);
      ls[i] = f2bf(x - bf2f(hs[i]));
    }
    size_t o = (size_t)(n0 + n) * K + k0 + c4;
    *(uint2*)(Wth + o) = make_uint2(hs[0] | ((unsigned)hs[1] << 16), hs[2] | ((unsigned)hs[3] << 16));
    *(uint2*)(Wtl + o) = make_uint2(ls[0] | ((unsigned)ls[1] << 16), ls[2] | ((unsigned)ls[3] << 16));
  }
}

// ---- split-precision GEMM with global_load_lds staging ----
// C[M][512] = (Ah+Al)[M][K] @ (Bh+Bl)[K][512] + bias ; B transposed [512][K].
// BM=128 BN=64 BK=32. 256 thr = 4 waves (2x2 of 64x32).
// LDS layout: unpadded [row][32] u16; 16B granules XOR-swizzled:
//   LDS (row, p) holds global (row, p ^ swz(row)), swz(r)=(r&3)^((r>>2)&3)
// -> ds_read_b128 fragment reads are 2-way bank aliased (free, m136).
__global__ __launch_bounds__(256, 2) void gemm_split_kernel(
    const u16* __restrict__ Ah, const u16* __restrict__ Al, int lda,
    const u16* __restrict__ Bth, const u16* __restrict__ Btl, int K,
    const float* __restrict__ bias,
    void* __restrict__ out0, void* __restrict__ out1, int mode)
{
  __shared__ __align__(16) u16 sAh[128 * 32], sAl[128 * 32];
  __shared__ __align__(16) u16 sBh[64 * 32],  sBl[64 * 32];
  int tid = threadIdx.x;
  int lane = tid & 63, w = tid >> 6, quad = lane >> 4, l15 = lane & 15;
  int wm = w & 1, wn = w >> 1;
  int m0 = blockIdx.x * 128, n0 = blockIdx.y * 64;

  f32x4_t acc[4][2];
#pragma unroll
  for (int i = 0; i < 4; i++)
#pragma unroll
    for (int j = 0; j < 2; j++)
#pragma unroll
      for (int r = 0; r < 4; r++) acc[i][j][r] = 0.f;

  // staging lane constants: granule G enumerates LDS slots linearly.
  int lrow = lane >> 2;                               // row-within-16-group
  int swzS = ((lane >> 2) & 3) ^ ((lane >> 4) & 3);   // == swz(row) for our row mapping
  int gkq  = ((lane & 3) ^ swzS) * 8;                 // global k-offset (elems)
  const u16* pAh0 = Ah + (size_t)(m0 + w * 32 + lrow) * lda + gkq;
  const u16* pAh1 = Ah + (size_t)(m0 + w * 32 + 16 + lrow) * lda + gkq;
  const u16* pAl0 = Al + (size_t)(m0 + w * 32 + lrow) * lda + gkq;
  const u16* pAl1 = Al + (size_t)(m0 + w * 32 + 16 + lrow) * lda + gkq;
  const u16* pBh0 = Bth + (size_t)(n0 + w * 16 + lrow) * K + gkq;
  const u16* pBl0 = Btl + (size_t)(n0 + w * 16 + lrow) * K + gkq;
  u16* dAh = sAh + w * 1024;
  u16* dAl = sAl + w * 1024;
  u16* dBh = sBh + w * 512;
  u16* dBl = sBl + w * 512;

  // fragment-read lane constant
  int pq = (quad ^ ((l15 & 3) ^ ((l15 >> 2) & 3))) * 8;

  for (int k0 = 0; k0 < K; k0 += 32){
    __syncthreads();
    gl2lds16(pAh0 + k0, dAh);
    gl2lds16(pAh1 + k0, dAh + 512);
    gl2lds16(pAl0 + k0, dAl);
    gl2lds16(pAl1 + k0, dAl + 512);
    gl2lds16(pBh0 + k0, dBh);
    gl2lds16(pBl0 + k0, dBl);
    __syncthreads();

    bf16x8_t aH[4], aL[4], bH[2], bL[2];
#pragma unroll
    for (int mi = 0; mi < 4; mi++){
      int ad = (wm * 64 + mi * 16 + l15) * 32 + pq;
      aH[mi] = *(const bf16x8_t*)&sAh[ad];
      aL[mi] = *(const bf16x8_t*)&sAl[ad];
    }
#pragma unroll
    for (int ni = 0; ni < 2; ni++){
      int bd = (wn * 32 + ni * 16 + l15) * 32 + pq;
      bH[ni] = *(const bf16x8_t*)&sBh[bd];
      bL[ni] = *(const bf16x8_t*)&sBl[bd];
    }
#pragma unroll
    for (int mi = 0; mi < 4; mi++)
#pragma unroll
      for (int ni = 0; ni < 2; ni++){
        acc[mi][ni] = __builtin_amdgcn_mfma_f32_16x16x32_bf16(aH[mi], bH[ni], acc[mi][ni], 0, 0, 0);
        acc[mi][ni] = __builtin_amdgcn_mfma_f32_16x16x32_bf16(aH[mi], bL[ni], acc[mi][ni], 0, 0, 0);
        acc[mi][ni] = __builtin_amdgcn_mfma_f32_16x16x32_bf16(aL[mi], bH[ni], acc[mi][ni], 0, 0, 0);
      }
  }

#pragma unroll
  for (int mi = 0; mi < 4; mi++)
#pragma unroll
    for (int ni = 0; ni < 2; ni++){
      int gn = n0 + wn * 32 + ni * 16 + l15;
      float bs = bias[gn];
      int gm0 = m0 + wm * 64 + mi * 16 + quad * 4;
#pragma unroll
      for (int r = 0; r < 4; r++){
        float v = acc[mi][ni][r] + bs;
        int gm = gm0 + r;
        if (mode == 0){
          u16 hb = f2bf(v);
          ((u16*)out0)[(size_t)gm * 512 + gn] = hb;
          ((u16*)out1)[(size_t)gm * 512 + gn] = f2bf(v - bf2f(hb));
        } else if (mode == 1){
          int bb = gm >> 11, s = gm & 2047;
          int hh = gn >> 6, d = gn & 63;
          ((u16*)out0)[((size_t)((bb * 8 + hh) * 64 + d) << 11) + s] = f2bf(v);
        } else {
          ((float*)out0)[(size_t)gm * 512 + gn] = v;
        }
      }
    }
}

// ---- flash attention, no-max streaming (scores provably bounded) ----
// p = M * exp(scale*qk*M); l = sum p (per-lane partial, one final reduce);
// O = sum p*V; out = O / l.
// K/V tiles staged via global_load_lds; rows of 8 granules, g' = g ^ (row&7).
// grid (32, 32), 256 thr = 4 waves x 16 q-rows; 4 blocks/CU (exactly 1024).
__global__ __launch_bounds__(256, 4) void flash_kernel(
    const u16* __restrict__ Qh, const u16* __restrict__ Ql,
    const u16* __restrict__ Kh, const u16* __restrict__ Kl,
    const u16* __restrict__ Vt, const float* __restrict__ Mm,
    u16* __restrict__ Oh, u16* __restrict__ Ol)
{
  __shared__ __align__(16) u16 sKh[64 * 64], sKl[64 * 64], sVt[64 * 64];
  __shared__ __align__(16) u16 sP[64 * 72];   // 144B rows (16B-aligned), 2-way banks
  int tid = threadIdx.x, lane = tid & 63, w = tid >> 6, quad = lane >> 4, l15 = lane & 15;
  int bh = blockIdx.y, b = bh >> 3, h = bh & 7;
  int q0 = blockIdx.x * 64;
  const float scale = 0.125f;

  // Q fragments in registers for the whole kernel
  int qrow = q0 + w * 16 + l15;
  const u16* qpH = Qh + ((size_t)(b * 2048 + qrow)) * 512 + h * 64 + quad * 8;
  const u16* qpL = Ql + ((size_t)(b * 2048 + qrow)) * 512 + h * 64 + quad * 8;
  bf16x8_t qH[2], qL[2];
  qH[0] = *(const bf16x8_t*)qpH;  qH[1] = *(const bf16x8_t*)(qpH + 32);
  qL[0] = *(const bf16x8_t*)qpL;  qL[1] = *(const bf16x8_t*)(qpL + 32);

  float lp[4] = {0.f, 0.f, 0.f, 0.f};
  f32x4_t Oacc[4];
#pragma unroll
  for (int ni = 0; ni < 4; ni++)
#pragma unroll
    for (int r = 0; r < 4; r++) Oacc[ni][r] = 0.f;

  // staging lane constants: G = w*128 + i*64 + lane; row = G>>3; p = lane&7
  int srow = lane >> 3;                                  // 0..7
  int gc = ((lane & 7) ^ ((lane >> 3) & 7)) * 8;         // swizzled col (elems)
  const u16* gKh0 = Kh + ((size_t)(b * 2048 + w * 16 + srow)) * 512 + h * 64 + gc;
  const u16* gKl0 = Kl + ((size_t)(b * 2048 + w * 16 + srow)) * 512 + h * 64 + gc;
  const u16* gVt0 = Vt + ((size_t)(bh * 64 + w * 16 + srow)) * 2048 + gc;
  u16* dKh = sKh + w * 1024;
  u16* dKl = sKl + w * 1024;
  u16* dVt = sVt + w * 1024;
  const float* Mbase = Mm + (size_t)b * 2048 * 2048 + (size_t)(q0 + w * 16) * 2048;

  int sw7 = l15 & 7;        // fragment-read row swizzle
  for (int k0 = 0; k0 < 2048; k0 += 64){
    __syncthreads();
    gl2lds16(gKh0 + (size_t)k0 * 512,        dKh);
    gl2lds16(gKh0 + (size_t)(k0 + 8) * 512,  dKh + 512);
    gl2lds16(gKl0 + (size_t)k0 * 512,        dKl);
    gl2lds16(gKl0 + (size_t)(k0 + 8) * 512,  dKl + 512);
    gl2lds16(gVt0 + k0,                      dVt);
    gl2lds16(gVt0 + 8 * 2048 + k0,           dVt + 512);
    __syncthreads();

    // M values (issued early; used after the QK MFMAs)
    float Mv[4][4];
#pragma unroll
    for (int ni = 0; ni < 4; ni++)
#pragma unroll
      for (int r = 0; r < 4; r++)
        Mv[ni][r] = Mbase[(size_t)(quad * 4 + r) * 2048 + k0 + ni * 16 + l15];

    // scores = Q . K^T (split-bf16, 3 MFMAs per (ni,ds))
    f32x4_t Sacc[4];
#pragma unroll
    for (int ni = 0; ni < 4; ni++)
#pragma unroll
      for (int r = 0; r < 4; r++) Sacc[ni][r] = 0.f;
#pragma unroll
    for (int ni = 0; ni < 4; ni++){
      int kb = (ni * 16 + l15) * 64;
#pragma unroll
      for (int ds = 0; ds < 2; ds++){
        int p = ((ds * 4 + quad) ^ sw7) * 8;
        bf16x8_t kH = *(const bf16x8_t*)&sKh[kb + p];
        bf16x8_t kL = *(const bf16x8_t*)&sKl[kb + p];
        Sacc[ni] = __builtin_amdgcn_mfma_f32_16x16x32_bf16(qH[ds], kH, Sacc[ni], 0, 0, 0);
        Sacc[ni] = __builtin_amdgcn_mfma_f32_16x16x32_bf16(qH[ds], kL, Sacc[ni], 0, 0, 0);
        Sacc[ni] = __builtin_amdgcn_mfma_f32_16x16x32_bf16(qL[ds], kH, Sacc[ni], 0, 0, 0);
      }
    }

    // p = M*exp(scale*qk*M); accumulate per-lane l; stash bf16 P for PV
#pragma unroll
    for (int ni = 0; ni < 4; ni++)
#pragma unroll
      for (int r = 0; r < 4; r++){
        float m = Mv[ni][r];
        float p = m * __expf(Sacc[ni][r] * scale * m);
        lp[r] += p;
        sP[(w * 16 + quad * 4 + r) * 72 + ni * 16 + l15] = f2bf(p);
      }

    // O += P @ V (wave-private sP rows; no barrier needed)
#pragma unroll
    for (int ds = 0; ds < 2; ds++){
      bf16x8_t pf = *(const bf16x8_t*)&sP[(w * 16 + l15) * 72 + ds * 32 + quad * 8];
#pragma unroll
      for (int ni = 0; ni < 4; ni++){
        int p = ((ds * 4 + quad) ^ sw7) * 8;
        bf16x8_t vf = *(const bf16x8_t*)&sVt[(ni * 16 + l15) * 64 + p];
        Oacc[ni] = __builtin_amdgcn_mfma_f32_16x16x32_bf16(pf, vf, Oacc[ni], 0, 0, 0);
      }
    }
  }

  // one cross-lane reduction of l (over the 16 k-columns held per quad-row)
#pragma unroll
  for (int r = 0; r < 4; r++){
#pragma unroll
    for (int off = 1; off < 16; off <<= 1)
      lp[r] += __shfl_xor(lp[r], off);
  }

  // epilogue: normalize, split hi/lo, write row-major [8192][512]
#pragma unroll
  for (int r = 0; r < 4; r++){
    float inv = 1.0f / lp[r];
    int q = q0 + w * 16 + quad * 4 + r;
    size_t rb = ((size_t)(b * 2048 + q)) * 512 + h * 64;
#pragma unroll
    for (int ni = 0; ni < 4; ni++){
      float v = Oacc[ni][r] * inv;
      int d = ni * 16 + l15;
      u16 hb = f2bf(v);
      Oh[rb + d] = hb;
      Ol[rb + d] = f2bf(v - bf2f(hb));
    }
  }
}

extern "C" void kernel_launch(void* const* d_in, const int* in_sizes, int n_in,
                              void* d_out, int out_size, void* d_ws, size_t ws_size,
                              hipStream_t stream)
{
  const float* gene = (const float*)d_in[0];
  const float* expr = (const float*)d_in[1];
  const float* Mm   = (const float*)d_in[2];
  const float* Wf   = (const float*)d_in[3];
  const float* bfv  = (const float*)d_in[4];
  const float* Wq   = (const float*)d_in[5];
  const float* bq   = (const float*)d_in[6];
  const float* Wk   = (const float*)d_in[7];
  const float* bk   = (const float*)d_in[8];
  const float* Wv   = (const float*)d_in[9];
  const float* bv   = (const float*)d_in[10];
  const float* Wo   = (const float*)d_in[11];
  const float* bo   = (const float*)d_in[12];
  float* out = (float*)d_out;

  char* ws = (char*)d_ws;
  size_t off = 0;
  auto alloc = [&](size_t bytes) -> void* {
    void* p = (void*)(ws + off);
    off += (bytes + 255) & ~(size_t)255;
    return p;
  };
  u16* Xh   = (u16*)alloc(8192ull * 1024 * 2);
  u16* Xl   = (u16*)alloc(8192ull * 1024 * 2);
  u16* Wfth = (u16*)alloc(512ull * 1024 * 2);
  u16* Wftl = (u16*)alloc(512ull * 1024 * 2);
  u16* Wqth = (u16*)alloc(512ull * 512 * 2);
  u16* Wqtl = (u16*)alloc(512ull * 512 * 2);
  u16* Wkth = (u16*)alloc(512ull * 512 * 2);
  u16* Wktl = (u16*)alloc(512ull * 512 * 2);
  u16* Wvth = (u16*)alloc(512ull * 512 * 2);
  u16* Wvtl = (u16*)alloc(512ull * 512 * 2);
  u16* Woth = (u16*)alloc(512ull * 512 * 2);
  u16* Wotl = (u16*)alloc(512ull * 512 * 2);
  u16* Fh   = (u16*)alloc(8192ull * 512 * 2);
  u16* Fl   = (u16*)alloc(8192ull * 512 * 2);
  u16* Qh   = (u16*)alloc(8192ull * 512 * 2);
  u16* Ql   = (u16*)alloc(8192ull * 512 * 2);
  u16* Kh   = (u16*)alloc(8192ull * 512 * 2);
  u16* Kl   = (u16*)alloc(8192ull * 512 * 2);
  u16* Vt   = (u16*)alloc(8192ull * 512 * 2);
  // X is dead after the V projection; attention output aliases it.
  u16* Oh = Xh;
  u16* Ol = Xl;

  split_concat_kernel<<<8192, 256, 0, stream>>>(gene, expr, Xh, Xl);
  transpose_split_kernel<<<dim3(16, 8), 256, 0, stream>>>(Wf, Wfth, Wftl, 1024, 512);
  transpose_split_kernel<<<dim3(8, 8),  256, 0, stream>>>(Wq, Wqth, Wqtl, 512, 512);
  transpose_split_kernel<<<dim3(8, 8),  256, 0, stream>>>(Wk, Wkth, Wktl, 512, 512);
  transpose_split_kernel<<<dim3(8, 8),  256, 0, stream>>>(Wv, Wvth, Wvtl, 512, 512);
  transpose_split_kernel<<<dim3(8, 8),  256, 0, stream>>>(Wo, Woth, Wotl, 512, 512);

  gemm_split_kernel<<<dim3(64, 8), 256, 0, stream>>>(Xh, Xl, 1024, Wfth, Wftl, 1024, bfv, Fh, Fl, 0);
  gemm_split_kernel<<<dim3(64, 8), 256, 0, stream>>>(Fh, Fl, 512, Wqth, Wqtl, 512, bq, Qh, Ql, 0);
  gemm_split_kernel<<<dim3(64, 8), 256, 0, stream>>>(Fh, Fl, 512, Wkth, Wktl, 512, bk, Kh, Kl, 0);
  gemm_split_kernel<<<dim3(64, 8), 256, 0, stream>>>(Xh + 512, Xl + 512, 1024, Wvth, Wvtl, 512, bv, Vt, nullptr, 1);
  flash_kernel<<<dim3(32, 32), 256, 0, stream>>>(Qh, Ql, Kh, Kl, Vt, Mm, Oh, Ol);
  gemm_split_kernel<<<dim3(64, 8), 256, 0, stream>>>(Oh, Ol, 512, Woth, Wotl, 512, bo, out, nullptr, 2);

  (void)in_sizes; (void)n_in; (void)out_size; (void)ws_size;
}

// Round 3
// 301.693 us; speedup vs baseline: 1.3957x; 1.2362x over previous
//
#include <hip/hip_runtime.h>

typedef unsigned short u16;
typedef __attribute__((ext_vector_type(8))) short bf16x8_t;
typedef __attribute__((ext_vector_type(4))) float f32x4_t;

__device__ __forceinline__ u16 f2bf(float x){
  union { float f; unsigned u; } v; v.f = x;
  unsigned r = v.u + 0x7FFFu + ((v.u >> 16) & 1u);
  return (u16)(r >> 16);
}
__device__ __forceinline__ float bf2f(u16 h){
  union { unsigned u; float f; } v; v.u = ((unsigned)h) << 16;
  return v.f;
}
__device__ __forceinline__ u16 hi16(float x){
  union { float f; unsigned u; } v; v.f = x;
  return (u16)(v.u >> 16);          // truncation: bias cancels in renormalization
}

// async global->LDS DMA, 16B/lane; data lands at base + lane*16.
__device__ __forceinline__ void gl2lds16(const u16* g, u16* l){
  __builtin_amdgcn_global_load_lds((const __attribute__((address_space(1))) void*)g,
                                   (__attribute__((address_space(3))) void*)l, 16, 0, 0);
}

// ---- X = [gene|expr] concat, split into hi/lo bf16. 8192 rows x 1024 cols ----
__global__ __launch_bounds__(256) void split_concat_kernel(
    const float* __restrict__ gene, const float* __restrict__ expr,
    u16* __restrict__ Xh, u16* __restrict__ Xl)
{
  size_t e = ((size_t)blockIdx.x * 256 + threadIdx.x) * 4;
  int row = (int)(e >> 10);
  int col = (int)(e & 1023);
  const float* src = (col < 512) ? (gene + (size_t)row * 512 + col)
                                 : (expr + (size_t)row * 512 + (col - 512));
  float4 v = *(const float4*)src;
  float a[4] = {v.x, v.y, v.z, v.w};
  u16 hs[4], ls[4];
#pragma unroll
  for (int i = 0; i < 4; i++){
    hs[i] = f2bf(a[i]);
    ls[i] = f2bf(a[i] - bf2f(hs[i]));
  }
  *(uint2*)(Xh + e) = make_uint2(hs[0] | ((unsigned)hs[1] << 16), hs[2] | ((unsigned)hs[3] << 16));
  *(uint2*)(Xl + e) = make_uint2(ls[0] | ((unsigned)ls[1] << 16), ls[2] | ((unsigned)ls[3] << 16));
}

// ---- all weight transposes in ONE launch. W [K][N] f32 -> Wt [N][K] bf16 (hi, optional lo)
__global__ __launch_bounds__(256) void transpose_all_kernel(
    const float* __restrict__ Wf, const float* __restrict__ Wq,
    const float* __restrict__ Wk, const float* __restrict__ Wv,
    const float* __restrict__ Wo,
    u16* __restrict__ Wfth, u16* __restrict__ Wftl,
    u16* __restrict__ Wqth, u16* __restrict__ Wkth,
    u16* __restrict__ Wvth, u16* __restrict__ Woth)
{
  __shared__ float t[64][65];
  int id = blockIdx.x;
  const float* W; u16* Th; u16* Tl; int K, kx, ny;
  if (id < 128){ W = Wf; Th = Wfth; Tl = Wftl; K = 1024; kx = id >> 3; ny = id & 7; }
  else {
    int tt = id - 128; int wi = tt >> 6; tt &= 63; kx = tt >> 3; ny = tt & 7; K = 512;
    W  = (wi == 0) ? Wq  : (wi == 1) ? Wk  : (wi == 2) ? Wv  : Wo;
    Th = (wi == 0) ? Wqth: (wi == 1) ? Wkth: (wi == 2) ? Wvth: Woth;
    Tl = nullptr;
  }
  int k0 = kx * 64, n0 = ny * 64;
  int tid = threadIdx.x;
  int r = tid >> 4;
  int c4 = (tid & 15) * 4;
#pragma unroll
  for (int p = 0; p < 4; p++){
    int k = p * 16 + r;
    float4 v = *(const float4*)(W + (size_t)(k0 + k) * 512 + n0 + c4);
    t[c4 + 0][k] = v.x; t[c4 + 1][k] = v.y; t[c4 + 2][k] = v.z; t[c4 + 3][k] = v.w;
  }
  __syncthreads();
#pragma unroll
  for (int p = 0; p < 4; p++){
    int n = p * 16 + r;
    u16 hs[4], ls[4];
#pragma unroll
    for (int i = 0; i < 4; i++){
      float x = t[n][c4 + i];
      hs[i] = f2bf(x);
      ls[i] = f2bf(x - bf2f(hs[i]));
    }
    size_t o = (size_t)(n0 + n) * K + k0 + c4;
    *(uint2*)(Th + o) = make_uint2(hs[0] | ((unsigned)hs[1] << 16), hs[2] | ((unsigned)hs[3] << 16));
    if (Tl)
      *(uint2*)(Tl + o) = make_uint2(ls[0] | ((unsigned)ls[1] << 16), ls[2] | ((unsigned)ls[3] << 16));
  }
}

// ---- GEMM, templated on split count and output mode ----
// C[M][512] = A[M][K] @ B[K][512] + bias ; B given transposed [512][K].
// SPLITS: 3 = aH*bH + aH*bL + aL*bH ; 2 = aH*bH + aL*bH ; 1 = aH*bH
// MODE: 0 = split bf16 out (o0=hi,o1=lo) ; 1 = bf16 row-major, scaled
//       2 = bf16 V^T per head [(b*8+h)*64+d][s] ; 3 = f32 row-major
// DUAL: blockIdx.y>=8 selects second (Bh1,bias1,outsec,sc1) set.
// BM=128 BN=64 BK=32; 256 thr = 4 waves (2x2 of 64x32); XOR-swizzled LDS granules.
template<int SPLITS, int MODE, int DUAL>
__global__ __launch_bounds__(256, 2) void gemm_kernel(
    const u16* __restrict__ Ah, const u16* __restrict__ Al, int lda,
    const u16* __restrict__ Bh0, const u16* __restrict__ Bl0,
    const u16* __restrict__ Bh1, int K,
    const float* __restrict__ bias0, const float* __restrict__ bias1,
    void* __restrict__ out0, void* __restrict__ out1, void* __restrict__ outsec,
    float sc0, float sc1)
{
  __shared__ __align__(16) u16 sAh[128 * 32];
  __shared__ __align__(16) u16 sAl[SPLITS >= 2 ? 128 * 32 : 8];
  __shared__ __align__(16) u16 sBh[64 * 32];
  __shared__ __align__(16) u16 sBl[SPLITS == 3 ? 64 * 32 : 8];
  int tid = threadIdx.x;
  int lane = tid & 63, w = tid >> 6, quad = lane >> 4, l15 = lane & 15;
  int wm = w & 1, wn = w >> 1;
  int m0 = blockIdx.x * 128;
  int side = DUAL ? (int)(blockIdx.y >> 3) : 0;
  int n0 = (DUAL ? (int)(blockIdx.y & 7) : (int)blockIdx.y) * 64;
  const u16* Bh = (DUAL && side) ? Bh1 : Bh0;
  const float* bias = (DUAL && side) ? bias1 : bias0;
  void* o0 = (DUAL && side) ? outsec : out0;
  float sc = (DUAL && side) ? sc1 : sc0;

  f32x4_t acc[4][2];
#pragma unroll
  for (int i = 0; i < 4; i++)
#pragma unroll
    for (int j = 0; j < 2; j++)
#pragma unroll
      for (int r = 0; r < 4; r++) acc[i][j][r] = 0.f;

  int lrow = lane >> 2;
  int swzS = ((lane >> 2) & 3) ^ ((lane >> 4) & 3);
  int gkq  = ((lane & 3) ^ swzS) * 8;
  const u16* pAh0 = Ah + (size_t)(m0 + w * 32 + lrow) * lda + gkq;
  const u16* pAh1 = Ah + (size_t)(m0 + w * 32 + 16 + lrow) * lda + gkq;
  const u16* pAl0 = (SPLITS >= 2) ? Al + (size_t)(m0 + w * 32 + lrow) * lda + gkq : nullptr;
  const u16* pAl1 = (SPLITS >= 2) ? Al + (size_t)(m0 + w * 32 + 16 + lrow) * lda + gkq : nullptr;
  const u16* pBh0 = Bh + (size_t)(n0 + w * 16 + lrow) * K + gkq;
  const u16* pBl0 = (SPLITS == 3) ? Bl0 + (size_t)(n0 + w * 16 + lrow) * K + gkq : nullptr;
  u16* dAh = sAh + w * 1024;
  u16* dAl = sAl + w * 1024;
  u16* dBh = sBh + w * 512;
  u16* dBl = sBl + w * 512;

  int pq = (quad ^ ((l15 & 3) ^ ((l15 >> 2) & 3))) * 8;

  for (int k0 = 0; k0 < K; k0 += 32){
    __syncthreads();
    gl2lds16(pAh0 + k0, dAh);
    gl2lds16(pAh1 + k0, dAh + 512);
    if constexpr (SPLITS >= 2){
      gl2lds16(pAl0 + k0, dAl);
      gl2lds16(pAl1 + k0, dAl + 512);
    }
    gl2lds16(pBh0 + k0, dBh);
    if constexpr (SPLITS == 3)
      gl2lds16(pBl0 + k0, dBl);
    __syncthreads();

    bf16x8_t aH[4], aL[4], bH[2], bL[2];
#pragma unroll
    for (int mi = 0; mi < 4; mi++){
      int ad = (wm * 64 + mi * 16 + l15) * 32 + pq;
      aH[mi] = *(const bf16x8_t*)&sAh[ad];
      if constexpr (SPLITS >= 2) aL[mi] = *(const bf16x8_t*)&sAl[ad];
    }
#pragma unroll
    for (int ni = 0; ni < 2; ni++){
      int bd = (wn * 32 + ni * 16 + l15) * 32 + pq;
      bH[ni] = *(const bf16x8_t*)&sBh[bd];
      if constexpr (SPLITS == 3) bL[ni] = *(const bf16x8_t*)&sBl[bd];
    }
#pragma unroll
    for (int mi = 0; mi < 4; mi++)
#pragma unroll
      for (int ni = 0; ni < 2; ni++){
        acc[mi][ni] = __builtin_amdgcn_mfma_f32_16x16x32_bf16(aH[mi], bH[ni], acc[mi][ni], 0, 0, 0);
        if constexpr (SPLITS == 3)
          acc[mi][ni] = __builtin_amdgcn_mfma_f32_16x16x32_bf16(aH[mi], bL[ni], acc[mi][ni], 0, 0, 0);
        if constexpr (SPLITS >= 2)
          acc[mi][ni] = __builtin_amdgcn_mfma_f32_16x16x32_bf16(aL[mi], bH[ni], acc[mi][ni], 0, 0, 0);
      }
  }

#pragma unroll
  for (int mi = 0; mi < 4; mi++)
#pragma unroll
    for (int ni = 0; ni < 2; ni++){
      int gn = n0 + wn * 32 + ni * 16 + l15;
      float bs = bias[gn];
      int gm0 = m0 + wm * 64 + mi * 16 + quad * 4;
#pragma unroll
      for (int r = 0; r < 4; r++){
        float v = acc[mi][ni][r] + bs;
        int gm = gm0 + r;
        if constexpr (MODE == 0){
          u16 hb = f2bf(v);
          ((u16*)o0)[(size_t)gm * 512 + gn] = hb;
          ((u16*)out1)[(size_t)gm * 512 + gn] = f2bf(v - bf2f(hb));
        } else if constexpr (MODE == 1){
          ((u16*)o0)[(size_t)gm * 512 + gn] = f2bf(v * sc);
        } else if constexpr (MODE == 2){
          int bb = gm >> 11, s = gm & 2047;
          int hh = gn >> 6, d = gn & 63;
          ((u16*)o0)[((size_t)((bb * 8 + hh) * 64 + d) << 11) + s] = f2bf(v);
        } else {
          ((float*)o0)[(size_t)gm * 512 + gn] = v;
        }
      }
    }
}

// ---- flash attention, no-max streaming, pure-bf16 QK ----
// Q pre-scaled by 0.125*log2(e); p = M * exp2(qk_s * M); l = sum p; O = sum p*V.
// grid (32, 32), 256 thr = 4 waves x 16 q-rows; 4 blocks/CU.
__global__ __launch_bounds__(256, 4) void flash_kernel(
    const u16* __restrict__ Qh, const u16* __restrict__ Kh,
    const u16* __restrict__ Vt, const float* __restrict__ Mm,
    u16* __restrict__ Oh)
{
  __shared__ __align__(16) u16 sKh[64 * 64], sVt[64 * 64];
  __shared__ __align__(16) u16 sP[64 * 72];
  int tid = threadIdx.x, lane = tid & 63, w = tid >> 6, quad = lane >> 4, l15 = lane & 15;
  int bh = blockIdx.y, b = bh >> 3, h = bh & 7;
  int q0 = blockIdx.x * 64;

  int qrow = q0 + w * 16 + l15;
  const u16* qp = Qh + ((size_t)(b * 2048 + qrow)) * 512 + h * 64 + quad * 8;
  bf16x8_t qH[2];
  qH[0] = *(const bf16x8_t*)qp;  qH[1] = *(const bf16x8_t*)(qp + 32);

  float lp[4] = {0.f, 0.f, 0.f, 0.f};
  f32x4_t Oacc[4];
#pragma unroll
  for (int ni = 0; ni < 4; ni++)
#pragma unroll
    for (int r = 0; r < 4; r++) Oacc[ni][r] = 0.f;

  int srow = lane >> 3;
  int gc = ((lane & 7) ^ ((lane >> 3) & 7)) * 8;
  const u16* gKh0 = Kh + ((size_t)(b * 2048 + w * 16 + srow)) * 512 + h * 64 + gc;
  const u16* gVt0 = Vt + ((size_t)(bh * 64 + w * 16 + srow)) * 2048 + gc;
  u16* dKh = sKh + w * 1024;
  u16* dVt = sVt + w * 1024;
  const float* Mbase = Mm + (size_t)b * 2048 * 2048 + (size_t)(q0 + w * 16) * 2048;

  // preload M for tile 0 (register prefetch pipeline)
  float Mc[4][4];
#pragma unroll
  for (int ni = 0; ni < 4; ni++)
#pragma unroll
    for (int r = 0; r < 4; r++)
      Mc[ni][r] = Mbase[(size_t)(quad * 4 + r) * 2048 + ni * 16 + l15];

  int sw7 = l15 & 7;
  for (int k0 = 0; k0 < 2048; k0 += 64){
    __syncthreads();
    gl2lds16(gKh0 + (size_t)k0 * 512,       dKh);
    gl2lds16(gKh0 + (size_t)(k0 + 8) * 512, dKh + 512);
    gl2lds16(gVt0 + k0,                     dVt);
    gl2lds16(gVt0 + 8 * 2048 + k0,          dVt + 512);
    __syncthreads();

    // prefetch next tile's M into registers (consumed next iteration)
    float Mn[4][4];
    bool hasNext = (k0 + 64) < 2048;
    if (hasNext){
#pragma unroll
      for (int ni = 0; ni < 4; ni++)
#pragma unroll
        for (int r = 0; r < 4; r++)
          Mn[ni][r] = Mbase[(size_t)(quad * 4 + r) * 2048 + (k0 + 64) + ni * 16 + l15];
    }

    // scores = Q . K^T (bf16)
    f32x4_t Sacc[4];
#pragma unroll
    for (int ni = 0; ni < 4; ni++)
#pragma unroll
      for (int r = 0; r < 4; r++) Sacc[ni][r] = 0.f;
#pragma unroll
    for (int ni = 0; ni < 4; ni++){
      int kb = (ni * 16 + l15) * 64;
#pragma unroll
      for (int ds = 0; ds < 2; ds++){
        int p = ((ds * 4 + quad) ^ sw7) * 8;
        bf16x8_t kH = *(const bf16x8_t*)&sKh[kb + p];
        Sacc[ni] = __builtin_amdgcn_mfma_f32_16x16x32_bf16(qH[ds], kH, Sacc[ni], 0, 0, 0);
      }
    }

    // p = M * exp2(s*M); accumulate per-lane l; truncation-store bf16 P
#pragma unroll
    for (int ni = 0; ni < 4; ni++)
#pragma unroll
      for (int r = 0; r < 4; r++){
        float m = Mc[ni][r];
        float p = m * __builtin_amdgcn_exp2f(Sacc[ni][r] * m);
        lp[r] += p;
        sP[(w * 16 + quad * 4 + r) * 72 + ni * 16 + l15] = hi16(p);
      }

    // O += P @ V (wave-private sP rows; no barrier needed)
#pragma unroll
    for (int ds = 0; ds < 2; ds++){
      bf16x8_t pf = *(const bf16x8_t*)&sP[(w * 16 + l15) * 72 + ds * 32 + quad * 8];
#pragma unroll
      for (int ni = 0; ni < 4; ni++){
        int p = ((ds * 4 + quad) ^ sw7) * 8;
        bf16x8_t vf = *(const bf16x8_t*)&sVt[(ni * 16 + l15) * 64 + p];
        Oacc[ni] = __builtin_amdgcn_mfma_f32_16x16x32_bf16(pf, vf, Oacc[ni], 0, 0, 0);
      }
    }

    if (hasNext){
#pragma unroll
      for (int ni = 0; ni < 4; ni++)
#pragma unroll
        for (int r = 0; r < 4; r++) Mc[ni][r] = Mn[ni][r];
    }
  }

#pragma unroll
  for (int r = 0; r < 4; r++){
#pragma unroll
    for (int off = 1; off < 16; off <<= 1)
      lp[r] += __shfl_xor(lp[r], off);
  }

#pragma unroll
  for (int r = 0; r < 4; r++){
    float inv = 1.0f / lp[r];
    int q = q0 + w * 16 + quad * 4 + r;
    size_t rb = ((size_t)(b * 2048 + q)) * 512 + h * 64;
#pragma unroll
    for (int ni = 0; ni < 4; ni++){
      float v = Oacc[ni][r] * inv;
      Oh[rb + ni * 16 + l15] = f2bf(v);
    }
  }
}

extern "C" void kernel_launch(void* const* d_in, const int* in_sizes, int n_in,
                              void* d_out, int out_size, void* d_ws, size_t ws_size,
                              hipStream_t stream)
{
  const float* gene = (const float*)d_in[0];
  const float* expr = (const float*)d_in[1];
  const float* Mm   = (const float*)d_in[2];
  const float* Wf   = (const float*)d_in[3];
  const float* bfv  = (const float*)d_in[4];
  const float* Wq   = (const float*)d_in[5];
  const float* bq   = (const float*)d_in[6];
  const float* Wk   = (const float*)d_in[7];
  const float* bk   = (const float*)d_in[8];
  const float* Wv   = (const float*)d_in[9];
  const float* bv   = (const float*)d_in[10];
  const float* Wo   = (const float*)d_in[11];
  const float* bo   = (const float*)d_in[12];
  float* out = (float*)d_out;

  char* ws = (char*)d_ws;
  size_t off = 0;
  auto alloc = [&](size_t bytes) -> void* {
    void* p = (void*)(ws + off);
    off += (bytes + 255) & ~(size_t)255;
    return p;
  };
  u16* Xh   = (u16*)alloc(8192ull * 1024 * 2);
  u16* Xl   = (u16*)alloc(8192ull * 1024 * 2);
  u16* Wfth = (u16*)alloc(512ull * 1024 * 2);
  u16* Wftl = (u16*)alloc(512ull * 1024 * 2);
  u16* Wqth = (u16*)alloc(512ull * 512 * 2);
  u16* Wkth = (u16*)alloc(512ull * 512 * 2);
  u16* Wvth = (u16*)alloc(512ull * 512 * 2);
  u16* Woth = (u16*)alloc(512ull * 512 * 2);
  u16* Fh   = (u16*)alloc(8192ull * 512 * 2);
  u16* Fl   = (u16*)alloc(8192ull * 512 * 2);
  u16* Qh   = (u16*)alloc(8192ull * 512 * 2);
  u16* Kh   = (u16*)alloc(8192ull * 512 * 2);
  u16* Vt   = (u16*)alloc(8192ull * 512 * 2);
  // X is dead after the V projection; attention output aliases it.
  u16* Oh = Xh;

  const float QSC = 0.1803368801f;   // 0.125 * log2(e) — folded into Q, exp via exp2

  split_concat_kernel<<<8192, 256, 0, stream>>>(gene, expr, Xh, Xl);
  transpose_all_kernel<<<384, 256, 0, stream>>>(Wf, Wq, Wk, Wv, Wo,
                                                Wfth, Wftl, Wqth, Wkth, Wvth, Woth);

  // fused = X @ Wf + bf (full split, split output)
  gemm_kernel<3, 0, 0><<<dim3(64, 8), 256, 0, stream>>>(
      Xh, Xl, 1024, Wfth, Wftl, nullptr, 1024, bfv, nullptr, Fh, Fl, nullptr, 1.f, 1.f);
  // Q (pre-scaled) and K in one dual dispatch (A-split x W-hi)
  gemm_kernel<2, 1, 1><<<dim3(64, 16), 256, 0, stream>>>(
      Fh, Fl, 512, Wqth, nullptr, Wkth, 512, bq, bk, Qh, nullptr, Kh, QSC, 1.f);
  // V = expr @ Wv + bv -> bf16 V^T per head (A-split x W-hi)
  gemm_kernel<2, 2, 0><<<dim3(64, 8), 256, 0, stream>>>(
      Xh + 512, Xl + 512, 1024, Wvth, nullptr, nullptr, 512, bv, nullptr, Vt, nullptr, nullptr, 1.f, 1.f);
  // attention
  flash_kernel<<<dim3(32, 32), 256, 0, stream>>>(Qh, Kh, Vt, Mm, Oh);
  // out = O @ Wo + bo -> f32 (pure bf16)
  gemm_kernel<1, 3, 0><<<dim3(64, 8), 256, 0, stream>>>(
      Oh, nullptr, 512, Woth, nullptr, nullptr, 512, bo, nullptr, out, nullptr, nullptr, 1.f, 1.f);

  (void)in_sizes; (void)n_in; (void)out_size; (void)ws_size;
}